// Round 2
// baseline (446.232 us; speedup 1.0000x reference)
//
#include <hip/hip_runtime.h>
#include <math.h>

// SSIM loss: bilinear-resize input (384->512, align_corners) then SSIM vs target
// over 11x11 Gaussian windows (VALID), mean over (32,3,502,502), loss = clip(1-mean,0,1).
// Round 1: identical to round 0 (infra failure, no kernel evidence).

constexpr int KS   = 11;
constexpr int TILE = 32;
constexpr int REG  = TILE + KS - 1;   // 42
constexpr int HI = 384, WI = 384;
constexpr int HO = 512, WO = 512;
constexpr int OUTD = HO - KS + 1;     // 502
constexpr int NPLANE = 96;            // 32*3
constexpr float C1 = 1.0e-4f;         // (0.01*1)^2
constexpr float C2 = 9.0e-4f;         // (0.03*1)^2

__global__ __launch_bounds__(256)
void ssim_fused(const float* __restrict__ input, const float* __restrict__ target,
                double* __restrict__ accum)
{
    __shared__ float g[KS];
    __shared__ __align__(16) float s1[REG][REG + 2];   // img1 region (pad to 44 floats)
    __shared__ __align__(16) float s2[REG][REG + 2];   // img2 region
    __shared__ __align__(16) float h[5][REG][TILE];    // horizontal-conv intermediates
    __shared__ int   yo0[REG], yo1[REG];
    __shared__ float ywt[REG];
    __shared__ int   xo0[REG], xo1[REG];
    __shared__ float xwt[REG];
    __shared__ double wave_sums[4];

    const int tid = threadIdx.x;
    const int bc  = blockIdx.z;
    const int oy0 = blockIdx.y * TILE;
    const int ox0 = blockIdx.x * TILE;

    // Gaussian weights (normalized), f32 is plenty for 2e-2 threshold
    if (tid == 0) {
        float tmp[KS]; float s = 0.f;
        #pragma unroll
        for (int i = 0; i < KS; ++i) {
            float d = (float)(i - KS / 2);
            tmp[i] = expf(-d * d / (2.f * 1.5f * 1.5f));
            s += tmp[i];
        }
        #pragma unroll
        for (int i = 0; i < KS; ++i) g[i] = tmp[i] / s;
    }
    // per-axis bilinear tables (align_corners=True)
    if (tid < REG) {
        int r = oy0 + tid; if (r > HO - 1) r = HO - 1;
        double p = (double)r * (HI - 1) / (HO - 1);
        int i0 = (int)p;
        int i1 = i0 + 1; if (i1 > HI - 1) i1 = HI - 1;
        yo0[tid] = i0 * WI; yo1[tid] = i1 * WI; ywt[tid] = (float)(p - i0);
    }
    if (tid >= 64 && tid < 64 + REG) {
        int t = tid - 64;
        int c = ox0 + t; if (c > WO - 1) c = WO - 1;
        double p = (double)c * (WI - 1) / (WO - 1);
        int i0 = (int)p;
        int i1 = i0 + 1; if (i1 > WI - 1) i1 = WI - 1;
        xo0[t] = i0; xo1[t] = i1; xwt[t] = (float)(p - i0);
    }
    __syncthreads();

    const float* ip = input  + (size_t)bc * HI * WI;
    const float* tp = target + (size_t)bc * HO * WO;

    // stage img1 (bilinear on the fly) and img2 region into LDS
    for (int idx = tid; idx < REG * REG; idx += 256) {
        int ry = idx / REG, rx = idx - ry * REG;
        float wy = ywt[ry], wx = xwt[rx];
        int o0 = yo0[ry], o1 = yo1[ry], x0 = xo0[rx], x1 = xo1[rx];
        float v00 = ip[o0 + x0], v01 = ip[o0 + x1];
        float v10 = ip[o1 + x0], v11 = ip[o1 + x1];
        float top = v00 + wx * (v01 - v00);
        float bot = v10 + wx * (v11 - v10);
        s1[ry][rx] = top + wy * (bot - top);

        int gy = oy0 + ry; if (gy > HO - 1) gy = HO - 1;
        int gx = ox0 + rx; if (gx > WO - 1) gx = WO - 1;
        s2[ry][rx] = tp[gy * WO + gx];
    }
    __syncthreads();

    // horizontal pass: 42 rows x 8 groups of 4 outputs = 336 items
    for (int item = tid; item < REG * (TILE / 4); item += 256) {
        int ry = item >> 3;
        int x0 = (item & 7) * 4;
        float4 a0 = *(const float4*)&s1[ry][x0];
        float4 a1 = *(const float4*)&s1[ry][x0 + 4];
        float4 a2 = *(const float4*)&s1[ry][x0 + 8];
        float4 a3 = *(const float4*)&s1[ry][x0 + 12];
        float4 b0 = *(const float4*)&s2[ry][x0];
        float4 b1 = *(const float4*)&s2[ry][x0 + 4];
        float4 b2 = *(const float4*)&s2[ry][x0 + 8];
        float4 b3 = *(const float4*)&s2[ry][x0 + 12];
        float av[16] = {a0.x,a0.y,a0.z,a0.w, a1.x,a1.y,a1.z,a1.w,
                        a2.x,a2.y,a2.z,a2.w, a3.x,a3.y,a3.z,a3.w};
        float bv[16] = {b0.x,b0.y,b0.z,b0.w, b1.x,b1.y,b1.z,b1.w,
                        b2.x,b2.y,b2.z,b2.w, b3.x,b3.y,b3.z,b3.w};
        float h1[4] = {0,0,0,0}, h2[4] = {0,0,0,0};
        float h11[4] = {0,0,0,0}, h22[4] = {0,0,0,0}, h12[4] = {0,0,0,0};
        #pragma unroll
        for (int k = 0; k < 4; ++k) {
            #pragma unroll
            for (int j = 0; j < KS; ++j) {
                float a = av[k + j], b = bv[k + j], w = g[j];
                float ga = w * a, gb = w * b;
                h1[k]  += ga;
                h2[k]  += gb;
                h11[k] = fmaf(ga, a, h11[k]);
                h22[k] = fmaf(gb, b, h22[k]);
                h12[k] = fmaf(ga, b, h12[k]);
            }
        }
        *(float4*)&h[0][ry][x0] = make_float4(h1[0],  h1[1],  h1[2],  h1[3]);
        *(float4*)&h[1][ry][x0] = make_float4(h2[0],  h2[1],  h2[2],  h2[3]);
        *(float4*)&h[2][ry][x0] = make_float4(h11[0], h11[1], h11[2], h11[3]);
        *(float4*)&h[3][ry][x0] = make_float4(h22[0], h22[1], h22[2], h22[3]);
        *(float4*)&h[4][ry][x0] = make_float4(h12[0], h12[1], h12[2], h12[3]);
    }
    __syncthreads();

    // vertical pass + SSIM: each thread 4 consecutive y at one x -> 256 items
    double local = 0.0;
    {
        int lx  = tid & 31;
        int ly0 = (tid >> 5) * 4;
        int oy  = oy0 + ly0, ox = ox0 + lx;
        float acc[5][4];
        #pragma unroll
        for (int c = 0; c < 5; ++c) {
            float win[14];
            #pragma unroll
            for (int r = 0; r < 14; ++r) win[r] = h[c][ly0 + r][lx];
            #pragma unroll
            for (int k = 0; k < 4; ++k) {
                float s = 0.f;
                #pragma unroll
                for (int j = 0; j < KS; ++j) s = fmaf(g[j], win[k + j], s);
                acc[c][k] = s;
            }
        }
        float lsum = 0.f;
        #pragma unroll
        for (int k = 0; k < 4; ++k) {
            if (oy + k < OUTD && ox < OUTD) {
                float mu1 = acc[0][k], mu2 = acc[1][k];
                float mu1s = mu1 * mu1, mu2s = mu2 * mu2, mu12 = mu1 * mu2;
                float sg1  = acc[2][k] - mu1s;
                float sg2  = acc[3][k] - mu2s;
                float sg12 = acc[4][k] - mu12;
                float v1 = 2.f * sg12 + C2;
                float v2 = sg1 + sg2 + C2;
                float num = (2.f * mu12 + C1) * v1;
                float den = (mu1s + mu2s + C1) * v2;
                lsum += num / den;
            }
        }
        local = (double)lsum;
    }

    // block reduction: wave64 shuffle + LDS across 4 waves
    #pragma unroll
    for (int off = 32; off > 0; off >>= 1) local += __shfl_down(local, off);
    int wave = tid >> 6, lane = tid & 63;
    if (lane == 0) wave_sums[wave] = local;
    __syncthreads();
    if (tid == 0) {
        double s = wave_sums[0] + wave_sums[1] + wave_sums[2] + wave_sums[3];
        atomicAdd(accum, s);
    }
}

__global__ void ssim_finalize(const double* __restrict__ accum, float* __restrict__ out)
{
    if (threadIdx.x == 0 && blockIdx.x == 0) {
        double mean = accum[0] / ((double)NPLANE * OUTD * OUTD);
        double l = 1.0 - mean;
        if (l < 0.0) l = 0.0;
        if (l > 1.0) l = 1.0;
        out[0] = (float)l;
    }
}

extern "C" void kernel_launch(void* const* d_in, const int* in_sizes, int n_in,
                              void* d_out, int out_size, void* d_ws, size_t ws_size,
                              hipStream_t stream)
{
    const float* input  = (const float*)d_in[0];   // [32,3,384,384]
    const float* target = (const float*)d_in[1];   // [32,3,512,512]
    float* out = (float*)d_out;
    double* accum = (double*)d_ws;

    hipMemsetAsync(accum, 0, sizeof(double), stream);

    dim3 grid((OUTD + TILE - 1) / TILE, (OUTD + TILE - 1) / TILE, NPLANE);
    ssim_fused<<<grid, dim3(256), 0, stream>>>(input, target, accum);
    ssim_finalize<<<1, 64, 0, stream>>>(accum, out);
}